// Round 18
// baseline (139.711 us; speedup 1.0000x reference)
//
#include <hip/hip_runtime.h>
#include <hip/hip_bf16.h>

// Problem constants (SigmaMoE): B=4, T=2048 -> NT=8192 tokens
#define NT   8192
#define DM   1024
#define NE   16
#define ES   256
#define TOPK 4
#define CAP  8192   // per-expert token capacity (worst case)

typedef __attribute__((ext_vector_type(8))) short          short8;
typedef __attribute__((ext_vector_type(8))) unsigned short ushort8;
typedef __attribute__((ext_vector_type(4))) unsigned short us4;   // NOT "ushort4": HIP predefines that
typedef __attribute__((ext_vector_type(4))) float          f32x4;

__device__ __forceinline__ unsigned short f2bf(float f){
  union { float f; unsigned u; } v; v.f = f;
  return (unsigned short)((v.u + 0x7fffu + ((v.u >> 16) & 1u)) >> 16);  // RNE
}
__device__ __forceinline__ unsigned short f2h(float f){
  union { _Float16 h; unsigned short u; } v; v.h = (_Float16)f; return v.u;
}
__device__ __forceinline__ float h2f(unsigned short u){
  union { unsigned short u; _Float16 h; } v; v.u = u; return (float)v.h;
}

// async global->LDS, 16B/lane. LDS dest = wave-uniform base (+lane*16 in HW).
__device__ __forceinline__ void gload16(const unsigned short* g, unsigned char* l){
  __builtin_amdgcn_global_load_lds(
      (const __attribute__((address_space(1))) unsigned int*)g,
      (__attribute__((address_space(3))) unsigned int*)l, 16, 0, 0);
}

// ---- pre: router (blocks 0..511, 16 tokens each -> 2 blocks/CU so cross-block
//      wave overlap fills the per-chunk barrier drains, per R7->R8 lesson) +
//      transposes (blocks 512..8703). Block-uniform branch. ----
__global__ __launch_bounds__(256)
void pre_kernel(const float* __restrict__ hidden, const float* __restrict__ sel,
                const float* __restrict__ keys, const float* __restrict__ values,
                unsigned short* __restrict__ xb, unsigned short* __restrict__ kT,
                unsigned short* __restrict__ vT,
                int* __restrict__ cnt, int* __restrict__ tok,
                float* __restrict__ gate){
  __shared__ float xs[16][65];        // pad 65: stride mod 32 == 1 -> conflict-free
  __shared__ float sel_lds[64][16];
  __shared__ float scr[16][17];
  __shared__ int   lcnt[NE];
  __shared__ int   gb[NE];
  __shared__ float tile[32][33];

  const int tid = threadIdx.x;

  if (blockIdx.x >= 512){
    // ---------------- transpose path ----------------
    int id = blockIdx.x - 512;
    const float* src; unsigned short* dst; int R, C, e, r0, c0;
    if (id < 4096){                    // keys [16][1024][256] -> kT [16][256][1024]
      src = keys; dst = kT; R = DM; C = ES;
      e = id >> 8; int t = id & 255; r0 = (t >> 3) * 32; c0 = (t & 7) * 32;
    } else {                           // values [16][256][1024] -> vT [16][1024][256]
      id -= 4096;
      src = values; dst = vT; R = ES; C = DM;
      e = id >> 8; int t = id & 255; r0 = (t & 7) * 32; c0 = (t >> 3) * 32;
    }
    const float* sp = src + (size_t)e * R * C;
    unsigned short* dp = dst + (size_t)e * R * C;
    const int tx = tid & 31, ty = tid >> 5;      // 32 x 8
    #pragma unroll
    for (int i = 0; i < 4; i++)
      tile[ty + i*8][tx] = sp[(size_t)(r0 + ty + i*8) * C + c0 + tx];
    __syncthreads();
    #pragma unroll
    for (int i = 0; i < 4; i++)
      dp[(size_t)(c0 + ty + i*8) * R + r0 + tx] = f2bf(tile[tx][ty + i*8]);
    return;
  }

  // ---------------- router path (blocks 0..511, 16 tokens) ----------------
  const int t0 = blockIdx.x * 16;
  if (tid < NE) lcnt[tid] = 0;

  const int stok = tid >> 4, dseg = tid & 15;  // staging: 16 thr/token-row, 4 floats each
  const int tokc = tid & 15, eg  = tid >> 4;   // compute: 16 thr/token, 1 expert each
  float acc0 = 0.f;

  for (int kc = 0; kc < DM; kc += 64){
    __syncthreads();
    {   // stage sel chunk [64][16]
      int sdd = tid >> 2, se4 = (tid & 3) * 4;
      *reinterpret_cast<float4*>(&sel_lds[sdd][se4]) =
          *reinterpret_cast<const float4*>(sel + (size_t)(kc + sdd)*NE + se4);
    }
    {   // stage x chunk [16][64] + emit bf16 copy (float4 / us4 per thread)
      const float* g = hidden + (size_t)(t0 + stok)*DM + kc + dseg*4;
      float4 a = *reinterpret_cast<const float4*>(g);
      us4 r;
      r[0]=f2bf(a.x); r[1]=f2bf(a.y); r[2]=f2bf(a.z); r[3]=f2bf(a.w);
      *reinterpret_cast<us4*>(xb + (size_t)(t0 + stok)*DM + kc + dseg*4) = r;
      float* xr = &xs[stok][dseg*4];
      xr[0]=a.x; xr[1]=a.y; xr[2]=a.z; xr[3]=a.w;
    }
    __syncthreads();
    #pragma unroll 8
    for (int dd = 0; dd < 64; dd++)
      acc0 += xs[tokc][dd] * sel_lds[dd][eg];
  }
  scr[tokc][eg] = acc0;
  __syncthreads();

  int best[TOPK]; float gv[TOPK]; int loff[TOPK];
  if (tid < 16){
    unsigned used = 0;
    for (int k = 0; k < TOPK; k++){
      int be = 0; float bv = -1e30f;
      #pragma unroll
      for (int e = 0; e < NE; e++){      // strict > keeps lowest index on tie
        float v = scr[tid][e];
        bool ok = !((used >> e) & 1u) && (v > bv);
        if (ok){ bv = v; be = e; }
      }
      used |= 1u << be;
      best[k] = be;
      gv[k]   = 1.f / (1.f + expf(-bv));
      loff[k] = atomicAdd(&lcnt[be], 1);
    }
  }
  __syncthreads();
  if (tid < NE) gb[tid] = atomicAdd(&cnt[tid], lcnt[tid]);
  __syncthreads();
  if (tid < 16){
    int t = t0 + tid;
    #pragma unroll
    for (int k = 0; k < TOPK; k++){
      int pos = gb[best[k]] + loff[k];
      tok[best[k]*CAP + pos]  = t | (k << 16);   // token + rank tag
      gate[best[k]*CAP + pos] = gv[k];
    }
  }
}

// ---- grouped expert FFN (R14 exact, measured 88us): 64-token block,
//      2 blocks/CU, dbuf LDS staging with plain __syncthreads (all
//      counted-vmcnt grafts measured slower: R9 +8us, R15 +4us), (r>>1)&3
//      XOR swizzle (2-way = free), part in fp16. ----
__global__ __launch_bounds__(512, 4)
void ffn_kernel(const unsigned short* __restrict__ xb,   // [NT][DM] bf16
                const unsigned short* __restrict__ kT,   // [e][s=256][d=1024] bf16
                const unsigned short* __restrict__ vT,   // [e][d=1024][s=256] bf16
                const int* __restrict__ cnt, const int* __restrict__ tok,
                const float* __restrict__ gate,
                unsigned short* __restrict__ part){      // [4][NT][DM] fp16
  const int e  = blockIdx.x & (NE-1);
  const int n  = cnt[e];
  const int t0 = (blockIdx.x >> 4) * 64;
  if (t0 >= n) return;                      // block-uniform
  const int rows = min(64, n - t0);

  // sh: GEMM1 dbuf {X[64][32] 4KB @0 + K[256][32] 16KB @4096} x2 (stride 20480);
  //     GEMM2 aliases as vs[256][32] 16KB x2 (@0, @16384). Total 40KB.
  __shared__ __align__(16) unsigned char sh[40960];
  __shared__ __align__(16) unsigned char hsb[64*512];    // H [64][256] bf16, swizzled
  __shared__ int   toks[64];
  __shared__ int   rnk[64];
  __shared__ float gts[64];

  const int tid  = threadIdx.x;
  const int lane = tid & 63;
  const int wv   = tid >> 6;                // 8 waves
  const int lr   = lane & 15;
  const int kb16 = (lane >> 4) << 4;        // k-group byte offset
  const int hi4  = (lane >> 4) * 4;
  const int xo4  = ((lr >> 1) & 3) << 4;    // 2-way swizzle for 64B-row tiles
  const int xo8  = (lr & 7) << 4;           // swizzle for 512B-row hsb

  if (tid < 64){
    int idx = t0 + tid;
    int raw = tok[e*CAP + (idx < n ? idx : t0)];
    toks[tid] = raw & 0xFFFF;
    rnk[tid]  = raw >> 16;
    gts[tid]  = (idx < n) ? gate[e*CAP + idx] : 0.f;
  }
  __syncthreads();

  const unsigned short* kTe = kT + (size_t)e * ES * DM;
  const unsigned short* vTe = vT + (size_t)e * DM * ES;

  // staging maps: thread tid writes LDS bytes [tid*16,tid*16+16) = row tid>>2,
  // slot tid&3; source col pre-swizzled with the SAME involution.
  const int srow = tid >> 2;                       // 0..127
  const int scol = ((tid & 3) ^ ((srow >> 1) & 3)) * 8;
  const unsigned short* xsrc  = xb  + (size_t)toks[srow & 63]*DM + scol;  // waves 0-3 only
  const unsigned short* ksrc0 = kTe + (size_t)srow*DM         + scol;
  const unsigned short* ksrc1 = kTe + (size_t)(128 + srow)*DM + scol;
  const unsigned short* vsrc0 = vTe + (size_t)srow*ES         + scol;
  const unsigned short* vsrc1 = vTe + (size_t)(128 + srow)*ES + scol;

  const int mh = wv >> 2;                   // token half (32 rows)
  const int nq = wv & 3;                    // S/d quarter (64 cols)

  // prologue: stage GEMM1 chunk 0
  if (wv < 4) gload16(xsrc, sh + wv*1024);
  gload16(ksrc0, sh + 4096 + wv*1024);
  gload16(ksrc1, sh + 4096 + 8192 + wv*1024);

  const f32x4 fz = {0.f,0.f,0.f,0.f};
  f32x4 acc1[2][4];
  #pragma unroll
  for (int m = 0; m < 2; m++)
    #pragma unroll
    for (int nn = 0; nn < 4; nn++) acc1[m][nn] = fz;

  __syncthreads();                          // chunk 0 staged

  // ---- GEMM1: H[64][256] = X_tile @ K_e, BK=32, 32 chunks ----
  int q = 0;
  for (int c = 0; c < 32; c++){
    if (c < 31){
      int kc = (c+1)*32;
      unsigned char* bb = sh + (q^1)*20480;
      if (wv < 4) gload16(xsrc + kc, bb + wv*1024);
      gload16(ksrc0 + kc, bb + 4096 + wv*1024);
      gload16(ksrc1 + kc, bb + 4096 + 8192 + wv*1024);
    } else {
      // stage V chunk 0 (pass 0, s 0..31) into vs buf0 = sh+0 (GEMM1 buf0 dead)
      gload16(vsrc0, sh + wv*1024);
      gload16(vsrc1, sh + 8192 + wv*1024);
    }
    const unsigned char* xl = sh + q*20480;
    const unsigned char* kl = xl + 4096;
    short8 a[2], b[4];
    #pragma unroll
    for (int m = 0; m < 2; m++)
      a[m] = *reinterpret_cast<const short8*>(xl + (mh*32 + m*16 + lr)*64 + (kb16 ^ xo4));
    #pragma unroll
    for (int nn = 0; nn < 4; nn++)
      b[nn] = *reinterpret_cast<const short8*>(kl + (nq*64 + nn*16 + lr)*64 + (kb16 ^ xo4));
    #pragma unroll
    for (int nn = 0; nn < 4; nn++)
      #pragma unroll
      for (int m = 0; m < 2; m++)
        acc1[m][nn] = __builtin_amdgcn_mfma_f32_16x16x32_bf16(a[m], b[nn], acc1[m][nn], 0,0,0);
    __syncthreads();
    q ^= 1;
  }

  // H = bf16(gate * relu(acc1)) -> swizzled hsb
  #pragma unroll
  for (int m = 0; m < 2; m++)
    #pragma unroll
    for (int j = 0; j < 4; j++){
      int row = mh*32 + m*16 + hi4 + j;     // C/D: col=lane&15, row=(lane>>4)*4+j
      float g = gts[row];
      unsigned char* rbase = hsb + row*512;
      int rxo = (row & 7) << 4;
      #pragma unroll
      for (int nn = 0; nn < 4; nn++){
        int colb = (nq*64 + nn*16 + lr) * 2;
        float h = fmaxf(acc1[m][nn][j], 0.f) * g;
        *reinterpret_cast<unsigned short*>(rbase + (colb ^ rxo)) = f2bf(h);
      }
    }
  __syncthreads();                          // hsb visible; vs chunk 0 already drained

  // ---- GEMM2: part = H @ V_e. 4 d-passes (256 each) x 8 s-chunks (32 each). ----
  f32x4 acc2[2][4];
  #pragma unroll
  for (int m = 0; m < 2; m++)
    #pragma unroll
    for (int nn = 0; nn < 4; nn++) acc2[m][nn] = fz;

  for (int cc = 0; cc < 32; cc++){
    if (cc < 31){
      int nx = cc + 1;
      unsigned char* vb = sh + (nx & 1)*16384;
      const size_t soff = (size_t)(nx >> 3)*256*ES + (size_t)(nx & 7)*32;
      gload16(vsrc0 + soff, vb + wv*1024);
      gload16(vsrc1 + soff, vb + 8192 + wv*1024);
    }
    const unsigned char* vl = sh + (cc & 1)*16384;
    const int sb = (cc & 7) * 64;
    short8 a[2], b[4];
    #pragma unroll
    for (int m = 0; m < 2; m++)
      a[m] = *reinterpret_cast<const short8*>(hsb + (mh*32 + m*16 + lr)*512 + ((sb + kb16) ^ xo8));
    #pragma unroll
    for (int nn = 0; nn < 4; nn++)
      b[nn] = *reinterpret_cast<const short8*>(vl + (nq*64 + nn*16 + lr)*64 + (kb16 ^ xo4));
    #pragma unroll
    for (int nn = 0; nn < 4; nn++)
      #pragma unroll
      for (int m = 0; m < 2; m++)
        acc2[m][nn] = __builtin_amdgcn_mfma_f32_16x16x32_bf16(a[m], b[nn], acc2[m][nn], 0,0,0);

    if ((cc & 7) == 7){                     // end of a d-pass: write + reset
      int p4 = cc >> 3;
      #pragma unroll
      for (int m = 0; m < 2; m++)
        #pragma unroll
        for (int j = 0; j < 4; j++){
          int tokl = mh*32 + m*16 + hi4 + j;
          if (tokl < rows){
            unsigned short* pb = part + ((size_t)rnk[tokl]*NT + toks[tokl])*DM
                                      + p4*256 + nq*64 + lr;
            #pragma unroll
            for (int nn = 0; nn < 4; nn++)
              pb[nn*16] = f2h(acc2[m][nn][j]);
          }
        }
      #pragma unroll
      for (int m = 0; m < 2; m++)
        #pragma unroll
        for (int nn = 0; nn < 4; nn++) acc2[m][nn] = fz;
    }
    __syncthreads();
  }
}

// ---- gather: out[t][d] = sum_k part[k][t][d] (fp16), 16 elems/thread;
//      also writes reg_loss = 0 ----
__global__ __launch_bounds__(256)
void gather_kernel(const unsigned short* __restrict__ part, float* __restrict__ out){
  const size_t i   = (size_t)blockIdx.x * blockDim.x + threadIdx.x;
  const size_t off = i * 16;
  float s[16];
  #pragma unroll
  for (int j = 0; j < 16; j++) s[j] = 0.f;
  #pragma unroll
  for (int k = 0; k < TOPK; k++){
    const unsigned short* p = part + (size_t)k*NT*DM + off;
    ushort8 v0 = *reinterpret_cast<const ushort8*>(p);
    ushort8 v1 = *reinterpret_cast<const ushort8*>(p + 8);
    #pragma unroll
    for (int j = 0; j < 8; j++){ s[j] += h2f(v0[j]); s[8+j] += h2f(v1[j]); }
  }
  #pragma unroll
  for (int q = 0; q < 4; q++){
    float4 w = {s[q*4], s[q*4+1], s[q*4+2], s[q*4+3]};
    reinterpret_cast<float4*>(out + off)[q] = w;
  }
  if (i == 0) out[(size_t)NT*DM] = 0.f;   // reg_loss
}

extern "C" void kernel_launch(void* const* d_in, const int* in_sizes, int n_in,
                              void* d_out, int out_size, void* d_ws, size_t ws_size,
                              hipStream_t stream){
  const float* hidden = (const float*)d_in[0];   // [4,2048,1024]
  const float* sel    = (const float*)d_in[1];   // [1024,16]
  const float* keys   = (const float*)d_in[2];   // [16,1024,256]
  const float* values = (const float*)d_in[3];   // [16,256,1024]
  float* out = (float*)d_out;

  char* ws = (char*)d_ws;
  unsigned short* xb = (unsigned short*)ws;                              // 16 MB
  unsigned short* kT = (unsigned short*)(ws + (size_t)16*1024*1024);     //  8 MB
  unsigned short* vT = (unsigned short*)(ws + (size_t)24*1024*1024);     //  8 MB
  int*   cnt  = (int*)  (ws + (size_t)32*1024*1024);                     // 64 B
  int*   tok  = (int*)  (ws + (size_t)32*1024*1024 + 1024);              // 512 KB
  float* gate = (float*)(ws + (size_t)32*1024*1024 + 1024
                            + (size_t)NE*CAP*sizeof(int));               // 512 KB
  unsigned short* part = (unsigned short*)(ws + (size_t)34*1024*1024);   // 64 MB fp16 [4][NT][DM]

  hipMemsetAsync(cnt, 0, NE * sizeof(int), stream);

  pre_kernel<<<512 + 8192, 256, 0, stream>>>(hidden, sel, keys, values,
                                             xb, kT, vT, cnt, tok, gate);
  ffn_kernel<<<(CAP/64)*NE, 512, 0, stream>>>(xb, kT, vT, cnt, tok, gate, part);
  gather_kernel<<<(NT*DM/16)/256, 256, 0, stream>>>(part, out);
}

// Round 19
// 137.618 us; speedup vs baseline: 1.0152x; 1.0152x over previous
//
#include <hip/hip_runtime.h>
#include <hip/hip_bf16.h>

// Problem constants (SigmaMoE): B=4, T=2048 -> NT=8192 tokens
#define NT   8192
#define DM   1024
#define NE   16
#define ES   256
#define TOPK 4
#define CAP  8192   // per-expert token capacity (worst case)

typedef __attribute__((ext_vector_type(8))) short          short8;
typedef __attribute__((ext_vector_type(8))) unsigned short ushort8;
typedef __attribute__((ext_vector_type(4))) float          f32x4;

__device__ __forceinline__ unsigned short f2bf(float f){
  union { float f; unsigned u; } v; v.f = f;
  return (unsigned short)((v.u + 0x7fffu + ((v.u >> 16) & 1u)) >> 16);  // RNE
}
__device__ __forceinline__ unsigned short f2h(float f){
  union { _Float16 h; unsigned short u; } v; v.h = (_Float16)f; return v.u;
}
__device__ __forceinline__ float h2f(unsigned short u){
  union { unsigned short u; _Float16 h; } v; v.u = u; return (float)v.h;
}

// async global->LDS, 16B/lane. LDS dest = wave-uniform base (+lane*16 in HW).
__device__ __forceinline__ void gload16(const unsigned short* g, unsigned char* l){
  __builtin_amdgcn_global_load_lds(
      (const __attribute__((address_space(1))) unsigned int*)g,
      (__attribute__((address_space(3))) unsigned int*)l, 16, 0, 0);
}

// ---- pre: router (blocks 0..255, 32 tokens each — R18 measured 16-token
//      2-blocks/CU split as null-to-negative) + transposes (blocks 256..8447). ----
__global__ __launch_bounds__(256)
void pre_kernel(const float* __restrict__ hidden, const float* __restrict__ sel,
                const float* __restrict__ keys, const float* __restrict__ values,
                unsigned short* __restrict__ xb, unsigned short* __restrict__ kT,
                unsigned short* __restrict__ vT,
                int* __restrict__ cnt, int* __restrict__ tok,
                float* __restrict__ gate){
  __shared__ float xs[32][65];
  __shared__ float sel_lds[64][16];
  __shared__ float scr[32][17];
  __shared__ int   lcnt[NE];
  __shared__ int   gb[NE];
  __shared__ float tile[32][33];

  const int tid = threadIdx.x;

  if (blockIdx.x >= 256){
    // ---------------- transpose path ----------------
    int id = blockIdx.x - 256;
    const float* src; unsigned short* dst; int R, C, e, r0, c0;
    if (id < 4096){                    // keys [16][1024][256] -> kT [16][256][1024]
      src = keys; dst = kT; R = DM; C = ES;
      e = id >> 8; int t = id & 255; r0 = (t >> 3) * 32; c0 = (t & 7) * 32;
    } else {                           // values [16][256][1024] -> vT [16][1024][256]
      id -= 4096;
      src = values; dst = vT; R = ES; C = DM;
      e = id >> 8; int t = id & 255; r0 = (t & 7) * 32; c0 = (t >> 3) * 32;
    }
    const float* sp = src + (size_t)e * R * C;
    unsigned short* dp = dst + (size_t)e * R * C;
    const int tx = tid & 31, ty = tid >> 5;      // 32 x 8
    #pragma unroll
    for (int i = 0; i < 4; i++)
      tile[ty + i*8][tx] = sp[(size_t)(r0 + ty + i*8) * C + c0 + tx];
    __syncthreads();
    #pragma unroll
    for (int i = 0; i < 4; i++)
      dp[(size_t)(c0 + ty + i*8) * R + r0 + tx] = f2bf(tile[tx][ty + i*8]);
    return;
  }

  // ---------------- router path (blocks 0..255) ----------------
  const int t0 = blockIdx.x * 32;
  if (tid < NE) lcnt[tid] = 0;

  const int stok = tid >> 3, dseg = tid & 7;
  const int tokc = tid & 31, eg  = tid >> 5;
  float acc0 = 0.f, acc1 = 0.f;

  for (int kc = 0; kc < DM; kc += 64){
    __syncthreads();
    {
      int sdd = tid >> 2, se4 = (tid & 3) * 4;
      *reinterpret_cast<float4*>(&sel_lds[sdd][se4]) =
          *reinterpret_cast<const float4*>(sel + (size_t)(kc + sdd)*NE + se4);
    }
    {
      const float* g = hidden + (size_t)(t0 + stok)*DM + kc + dseg*8;
      float4 a = reinterpret_cast<const float4*>(g)[0];
      float4 b = reinterpret_cast<const float4*>(g)[1];
      ushort8 r;
      r[0]=f2bf(a.x); r[1]=f2bf(a.y); r[2]=f2bf(a.z); r[3]=f2bf(a.w);
      r[4]=f2bf(b.x); r[5]=f2bf(b.y); r[6]=f2bf(b.z); r[7]=f2bf(b.w);
      *reinterpret_cast<ushort8*>(xb + (size_t)(t0 + stok)*DM + kc + dseg*8) = r;
      float* xr = &xs[stok][dseg*8];
      xr[0]=a.x; xr[1]=a.y; xr[2]=a.z; xr[3]=a.w;
      xr[4]=b.x; xr[5]=b.y; xr[6]=b.z; xr[7]=b.w;
    }
    __syncthreads();
    #pragma unroll 8
    for (int dd = 0; dd < 64; dd++){
      float xv = xs[tokc][dd];
      float2 s = *reinterpret_cast<const float2*>(&sel_lds[dd][eg*2]);
      acc0 += xv * s.x;
      acc1 += xv * s.y;
    }
  }
  scr[tokc][eg*2]   = acc0;
  scr[tokc][eg*2+1] = acc1;
  __syncthreads();

  int best[TOPK]; float gv[TOPK]; int loff[TOPK];
  if (tid < 32){
    unsigned used = 0;
    for (int k = 0; k < TOPK; k++){
      int be = 0; float bv = -1e30f;
      #pragma unroll
      for (int e = 0; e < NE; e++){      // strict > keeps lowest index on tie
        float v = scr[tid][e];
        bool ok = !((used >> e) & 1u) && (v > bv);
        if (ok){ bv = v; be = e; }
      }
      used |= 1u << be;
      best[k] = be;
      gv[k]   = 1.f / (1.f + expf(-bv));
      loff[k] = atomicAdd(&lcnt[be], 1);
    }
  }
  __syncthreads();
  if (tid < NE) gb[tid] = atomicAdd(&cnt[tid], lcnt[tid]);
  __syncthreads();
  if (tid < 32){
    int t = t0 + tid;
    #pragma unroll
    for (int k = 0; k < TOPK; k++){
      int pos = gb[best[k]] + loff[k];
      tok[best[k]*CAP + pos]  = t | (k << 16);   // token + rank tag
      gate[best[k]*CAP + pos] = gv[k];
    }
  }
}

// ---- grouped expert FFN (best measured 88us): 64-token block, 2 blocks/CU,
//      dbuf LDS staging with plain __syncthreads (all counted-vmcnt grafts
//      measured slower: R9 +8us, R15 +4us), (r>>1)&3 XOR swizzle (2-way =
//      free), part in fp16. 64-token/2-per-CU is forced by problem shape:
//      M=32768 grouped x N=256 — larger tiles starve CUs (R7, R12). ----
__global__ __launch_bounds__(512, 4)
void ffn_kernel(const unsigned short* __restrict__ xb,   // [NT][DM] bf16
                const unsigned short* __restrict__ kT,   // [e][s=256][d=1024] bf16
                const unsigned short* __restrict__ vT,   // [e][d=1024][s=256] bf16
                const int* __restrict__ cnt, const int* __restrict__ tok,
                const float* __restrict__ gate,
                unsigned short* __restrict__ part){      // [4][NT][DM] fp16
  const int e  = blockIdx.x & (NE-1);
  const int n  = cnt[e];
  const int t0 = (blockIdx.x >> 4) * 64;
  if (t0 >= n) return;                      // block-uniform
  const int rows = min(64, n - t0);

  // sh: GEMM1 dbuf {X[64][32] 4KB @0 + K[256][32] 16KB @4096} x2 (stride 20480);
  //     GEMM2 aliases as vs[256][32] 16KB x2 (@0, @16384). Total 40KB.
  __shared__ __align__(16) unsigned char sh[40960];
  __shared__ __align__(16) unsigned char hsb[64*512];    // H [64][256] bf16, swizzled
  __shared__ int   toks[64];
  __shared__ int   rnk[64];
  __shared__ float gts[64];

  const int tid  = threadIdx.x;
  const int lane = tid & 63;
  const int wv   = tid >> 6;                // 8 waves
  const int lr   = lane & 15;
  const int kb16 = (lane >> 4) << 4;        // k-group byte offset
  const int hi4  = (lane >> 4) * 4;
  const int xo4  = ((lr >> 1) & 3) << 4;    // 2-way swizzle for 64B-row tiles
  const int xo8  = (lr & 7) << 4;           // swizzle for 512B-row hsb

  if (tid < 64){
    int idx = t0 + tid;
    int raw = tok[e*CAP + (idx < n ? idx : t0)];
    toks[tid] = raw & 0xFFFF;
    rnk[tid]  = raw >> 16;
    gts[tid]  = (idx < n) ? gate[e*CAP + idx] : 0.f;
  }
  __syncthreads();

  const unsigned short* kTe = kT + (size_t)e * ES * DM;
  const unsigned short* vTe = vT + (size_t)e * DM * ES;

  // staging maps: thread tid writes LDS bytes [tid*16,tid*16+16) = row tid>>2,
  // slot tid&3; source col pre-swizzled with the SAME involution.
  const int srow = tid >> 2;                       // 0..127
  const int scol = ((tid & 3) ^ ((srow >> 1) & 3)) * 8;
  const unsigned short* xsrc  = xb  + (size_t)toks[srow & 63]*DM + scol;  // waves 0-3 only
  const unsigned short* ksrc0 = kTe + (size_t)srow*DM         + scol;
  const unsigned short* ksrc1 = kTe + (size_t)(128 + srow)*DM + scol;
  const unsigned short* vsrc0 = vTe + (size_t)srow*ES         + scol;
  const unsigned short* vsrc1 = vTe + (size_t)(128 + srow)*ES + scol;

  const int mh = wv >> 2;                   // token half (32 rows)
  const int nq = wv & 3;                    // S/d quarter (64 cols)

  // prologue: stage GEMM1 chunk 0
  if (wv < 4) gload16(xsrc, sh + wv*1024);
  gload16(ksrc0, sh + 4096 + wv*1024);
  gload16(ksrc1, sh + 4096 + 8192 + wv*1024);

  const f32x4 fz = {0.f,0.f,0.f,0.f};
  f32x4 acc1[2][4];
  #pragma unroll
  for (int m = 0; m < 2; m++)
    #pragma unroll
    for (int nn = 0; nn < 4; nn++) acc1[m][nn] = fz;

  __syncthreads();                          // chunk 0 staged

  // ---- GEMM1: H[64][256] = X_tile @ K_e, BK=32, 32 chunks ----
  int q = 0;
  for (int c = 0; c < 32; c++){
    if (c < 31){
      int kc = (c+1)*32;
      unsigned char* bb = sh + (q^1)*20480;
      if (wv < 4) gload16(xsrc + kc, bb + wv*1024);
      gload16(ksrc0 + kc, bb + 4096 + wv*1024);
      gload16(ksrc1 + kc, bb + 4096 + 8192 + wv*1024);
    } else {
      // stage V chunk 0 (pass 0, s 0..31) into vs buf0 = sh+0 (GEMM1 buf0 dead)
      gload16(vsrc0, sh + wv*1024);
      gload16(vsrc1, sh + 8192 + wv*1024);
    }
    const unsigned char* xl = sh + q*20480;
    const unsigned char* kl = xl + 4096;
    short8 a[2], b[4];
    #pragma unroll
    for (int m = 0; m < 2; m++)
      a[m] = *reinterpret_cast<const short8*>(xl + (mh*32 + m*16 + lr)*64 + (kb16 ^ xo4));
    #pragma unroll
    for (int nn = 0; nn < 4; nn++)
      b[nn] = *reinterpret_cast<const short8*>(kl + (nq*64 + nn*16 + lr)*64 + (kb16 ^ xo4));
    #pragma unroll
    for (int nn = 0; nn < 4; nn++)
      #pragma unroll
      for (int m = 0; m < 2; m++)
        acc1[m][nn] = __builtin_amdgcn_mfma_f32_16x16x32_bf16(a[m], b[nn], acc1[m][nn], 0,0,0);
    __syncthreads();
    q ^= 1;
  }

  // H = bf16(gate * relu(acc1)) -> swizzled hsb
  #pragma unroll
  for (int m = 0; m < 2; m++)
    #pragma unroll
    for (int j = 0; j < 4; j++){
      int row = mh*32 + m*16 + hi4 + j;     // C/D: col=lane&15, row=(lane>>4)*4+j
      float g = gts[row];
      unsigned char* rbase = hsb + row*512;
      int rxo = (row & 7) << 4;
      #pragma unroll
      for (int nn = 0; nn < 4; nn++){
        int colb = (nq*64 + nn*16 + lr) * 2;
        float h = fmaxf(acc1[m][nn][j], 0.f) * g;
        *reinterpret_cast<unsigned short*>(rbase + (colb ^ rxo)) = f2bf(h);
      }
    }
  __syncthreads();                          // hsb visible; vs chunk 0 already drained

  // ---- GEMM2: part = H @ V_e. 4 d-passes (256 each) x 8 s-chunks (32 each). ----
  f32x4 acc2[2][4];
  #pragma unroll
  for (int m = 0; m < 2; m++)
    #pragma unroll
    for (int nn = 0; nn < 4; nn++) acc2[m][nn] = fz;

  for (int cc = 0; cc < 32; cc++){
    if (cc < 31){
      int nx = cc + 1;
      unsigned char* vb = sh + (nx & 1)*16384;
      const size_t soff = (size_t)(nx >> 3)*256*ES + (size_t)(nx & 7)*32;
      gload16(vsrc0 + soff, vb + wv*1024);
      gload16(vsrc1 + soff, vb + 8192 + wv*1024);
    }
    const unsigned char* vl = sh + (cc & 1)*16384;
    const int sb = (cc & 7) * 64;
    short8 a[2], b[4];
    #pragma unroll
    for (int m = 0; m < 2; m++)
      a[m] = *reinterpret_cast<const short8*>(hsb + (mh*32 + m*16 + lr)*512 + ((sb + kb16) ^ xo8));
    #pragma unroll
    for (int nn = 0; nn < 4; nn++)
      b[nn] = *reinterpret_cast<const short8*>(vl + (nq*64 + nn*16 + lr)*64 + (kb16 ^ xo4));
    #pragma unroll
    for (int nn = 0; nn < 4; nn++)
      #pragma unroll
      for (int m = 0; m < 2; m++)
        acc2[m][nn] = __builtin_amdgcn_mfma_f32_16x16x32_bf16(a[m], b[nn], acc2[m][nn], 0,0,0);

    if ((cc & 7) == 7){                     // end of a d-pass: write + reset
      int p4 = cc >> 3;
      #pragma unroll
      for (int m = 0; m < 2; m++)
        #pragma unroll
        for (int j = 0; j < 4; j++){
          int tokl = mh*32 + m*16 + hi4 + j;
          if (tokl < rows){
            unsigned short* pb = part + ((size_t)rnk[tokl]*NT + toks[tokl])*DM
                                      + p4*256 + nq*64 + lr;
            #pragma unroll
            for (int nn = 0; nn < 4; nn++)
              pb[nn*16] = f2h(acc2[m][nn][j]);
          }
        }
      #pragma unroll
      for (int m = 0; m < 2; m++)
        #pragma unroll
        for (int nn = 0; nn < 4; nn++) acc2[m][nn] = fz;
    }
    __syncthreads();
  }
}

// ---- gather: out[t][d] = sum_k part[k][t][d] (fp16), 16 elems/thread;
//      also writes reg_loss = 0 ----
__global__ __launch_bounds__(256)
void gather_kernel(const unsigned short* __restrict__ part, float* __restrict__ out){
  const size_t i   = (size_t)blockIdx.x * blockDim.x + threadIdx.x;
  const size_t off = i * 16;
  float s[16];
  #pragma unroll
  for (int j = 0; j < 16; j++) s[j] = 0.f;
  #pragma unroll
  for (int k = 0; k < TOPK; k++){
    const unsigned short* p = part + (size_t)k*NT*DM + off;
    ushort8 v0 = *reinterpret_cast<const ushort8*>(p);
    ushort8 v1 = *reinterpret_cast<const ushort8*>(p + 8);
    #pragma unroll
    for (int j = 0; j < 8; j++){ s[j] += h2f(v0[j]); s[8+j] += h2f(v1[j]); }
  }
  #pragma unroll
  for (int q = 0; q < 4; q++){
    float4 w = {s[q*4], s[q*4+1], s[q*4+2], s[q*4+3]};
    reinterpret_cast<float4*>(out + off)[q] = w;
  }
  if (i == 0) out[(size_t)NT*DM] = 0.f;   // reg_loss
}

extern "C" void kernel_launch(void* const* d_in, const int* in_sizes, int n_in,
                              void* d_out, int out_size, void* d_ws, size_t ws_size,
                              hipStream_t stream){
  const float* hidden = (const float*)d_in[0];   // [4,2048,1024]
  const float* sel    = (const float*)d_in[1];   // [1024,16]
  const float* keys   = (const float*)d_in[2];   // [16,1024,256]
  const float* values = (const float*)d_in[3];   // [16,256,1024]
  float* out = (float*)d_out;

  char* ws = (char*)d_ws;
  unsigned short* xb = (unsigned short*)ws;                              // 16 MB
  unsigned short* kT = (unsigned short*)(ws + (size_t)16*1024*1024);     //  8 MB
  unsigned short* vT = (unsigned short*)(ws + (size_t)24*1024*1024);     //  8 MB
  int*   cnt  = (int*)  (ws + (size_t)32*1024*1024);                     // 64 B
  int*   tok  = (int*)  (ws + (size_t)32*1024*1024 + 1024);              // 512 KB
  float* gate = (float*)(ws + (size_t)32*1024*1024 + 1024
                            + (size_t)NE*CAP*sizeof(int));               // 512 KB
  unsigned short* part = (unsigned short*)(ws + (size_t)34*1024*1024);   // 64 MB fp16 [4][NT][DM]

  hipMemsetAsync(cnt, 0, NE * sizeof(int), stream);

  pre_kernel<<<256 + 8192, 256, 0, stream>>>(hidden, sel, keys, values,
                                             xb, kT, vT, cnt, tok, gate);
  ffn_kernel<<<(CAP/64)*NE, 512, 0, stream>>>(xb, kT, vT, cnt, tok, gate, part);
  gather_kernel<<<(NT*DM/16)/256, 256, 0, stream>>>(part, out);
}